// Round 1
// 290.077 us; speedup vs baseline: 1.0415x; 1.0415x over previous
//
#include <hip/hip_runtime.h>
#include <math.h>

// Problem constants
#define Bq 8
#define Nq 8192
#define Dq 256
#define Qq 4
#define Kq 2048
#define Mq (Nq / Qq)
#define TT (Bq * Nq)                    // 65536 tokens
#define QUANT_ELEMS ((size_t)TT * Dq)   // 16777216

#define CAP1Q 4096
#define THRESH 3e-4f        // fp16 margin band (~12 sigma of fp16-input score error)

// ws layout (bytes)
#define WS_CNT_OFF    0u
#define WS_LIST_OFF   1024u      // 4*4096 ints  = 64 KB   -> [1024, 66560)
#define WS_PSC_OFF    66560u     // 4*4096*8 f32 = 512 KB  -> [66560, 590848)
#define WS_PCD_OFF    590848u    // 4*4096*8 i32 = 512 KB  -> [590848, 1115136)
#define WS_ENH_OFF    1115136u   // 4 MB fp16 swizzled codes
#define WS_ENP_OFF    5309440u   // 8 MB fp32 numpy-normalized codes -> ends 13698048
#define WS_PART_OFF   13698048u  // 2 MB float4 per-half top-2 partials [2][TT]

typedef __attribute__((ext_vector_type(8))) _Float16 f16x8;
typedef __attribute__((ext_vector_type(4))) _Float16 f16x4;
typedef __attribute__((ext_vector_type(4))) float    f32x4;

__device__ __forceinline__ void async_load16(const void* g, void* s) {
    __builtin_amdgcn_global_load_lds(
        (const __attribute__((address_space(1))) void*)g,
        (__attribute__((address_space(3))) void*)s, 16, 0, 0);
}

__device__ __forceinline__ float f32_div(float a, float b) {
    return (float)((double)a / (double)b);   // exact IEEE fp32 divide
}

// numpy pairwise norm of a 256-row, wave-parallel but BIT-EXACT vs the serial
// 8-accumulator + tree emulation (validated round 3). Lanes 0..15 active.
__device__ __forceinline__ float np_norm_wave(const float* __restrict__ src, int ln) {
#pragma clang fp contract(off)
    float r = 0.0f;
    if (ln < 16) {
        const float* p = src + (ln >> 3) * 128 + (ln & 7);
        #pragma unroll
        for (int m = 0; m < 16; ++m) { float v = p[m * 8]; r = r + v * v; }
    }
    float t = r + __shfl_xor(r, 1, 64);      // (r0+r1) ...
    t = t + __shfl_xor(t, 2, 64);            // (r0+r1)+(r2+r3) ...
    t = t + __shfl_xor(t, 4, 64);            // full 8-acc tree
    float b0 = __shfl(t, 0, 64);
    float b1 = __shfl(t, 8, 64);
    float n2 = b0 + b1;                      // pw(0:128) + pw(128:256)
    return fmaxf((float)sqrt((double)n2), 1e-12f);
}

// ---------------- prep: fused cvt (fp16 swizzled) + enp (numpy fp32) --------
__global__ __launch_bounds__(256) void prep_kernel(const float* __restrict__ embed,
                                                   char* __restrict__ enh,
                                                   float* __restrict__ enp) {
    int row = blockIdx.x * 4 + (threadIdx.x >> 6);   // 0..8191
    int ln  = threadIdx.x & 63;
    const float* src = embed + (size_t)row * Dq;

    // --- fp16 fast-normalized swizzled codes (identical to old cvt_kernel) ---
    float4 v = *(const float4*)(src + ln * 4);
    float s = v.x * v.x + v.y * v.y + v.z * v.z + v.w * v.w;
    #pragma unroll
    for (int m = 1; m < 64; m <<= 1) s += __shfl_xor(s, m, 64);
    float sx = 1.0f / fmaxf(sqrtf(s), 1e-12f);
    int q = row >> 11, k = row & 2047, Tb = k >> 5, c = k & 31;
    int g = ln >> 1, h = ln & 1;
    f16x4 o;
    o[0] = (_Float16)(v.x * sx); o[1] = (_Float16)(v.y * sx);
    o[2] = (_Float16)(v.z * sx); o[3] = (_Float16)(v.w * sx);
    char* dst = enh + ((size_t)(q * 64 + Tb)) * 16384 + c * 512 + ((g ^ c) << 4) + h * 8;
    *(f16x4*)dst = o;

    // --- numpy-exact normalized fp32 codes (identical to old enp_kernel) ---
    float nm = np_norm_wave(src, ln);
    float* dstp = enp + (size_t)row * Dq;
    #pragma unroll
    for (int e = 0; e < 4; ++e) dstp[ln * 4 + e] = f32_div(src[ln * 4 + e], nm);
}

// ---------------- stage 1: LDS-shared-B fp16 MFMA scoring, K-split 2-way ----
// grid 1024: bid = (w<<3)|(h<<2)|q ; each block scores 128 tokens x 1024 codes
// and writes per-half top-2 partials (b1,b2,ic) to part[h][t].
__global__ __launch_bounds__(256) void gemm_kernel(const float* __restrict__ x,
                                                   const char* __restrict__ enh,
                                                   float4* __restrict__ part) {
    __shared__ __align__(16) char es[2][16384];

    const int tid = threadIdx.x;
    const int wv  = tid >> 6;
    const int ln  = tid & 63;
    const int qd  = ln >> 4;
    const int l15 = ln & 15;

    const int bid = blockIdx.x;              // 0..1023
    const int q   = bid & 3;
    const int h   = (bid >> 2) & 1;          // codebook half
    const int w   = bid >> 3;                // 0..127
    const int t0  = (w >> 4) * Nq + q * Mq + (w & 15) * 128;
    const int t0w = t0 + wv * 32;

    f16x8 ah[2][8];
    #pragma unroll
    for (int mf = 0; mf < 2; ++mf) {
        const float* xr = x + (size_t)(t0w + mf * 16 + l15) * Dq + qd * 8;
        float4 xa[16];
        float s2 = 0.f;
        #pragma unroll
        for (int ch = 0; ch < 8; ++ch) {
            float4 u = *(const float4*)(xr + ch * 32);
            float4 v = *(const float4*)(xr + ch * 32 + 4);
            xa[2 * ch] = u; xa[2 * ch + 1] = v;
            s2 += u.x * u.x + u.y * u.y + u.z * u.z + u.w * u.w;
            s2 += v.x * v.x + v.y * v.y + v.z * v.z + v.w * v.w;
        }
        s2 += __shfl_xor(s2, 16, 64);
        s2 += __shfl_xor(s2, 32, 64);
        float sx = 1.0f / fmaxf(sqrtf(s2), 1e-12f);
        #pragma unroll
        for (int ch = 0; ch < 8; ++ch) {
            float4 u = xa[2 * ch], v = xa[2 * ch + 1];
            f16x8 f;
            f[0] = (_Float16)(u.x * sx); f[1] = (_Float16)(u.y * sx);
            f[2] = (_Float16)(u.z * sx); f[3] = (_Float16)(u.w * sx);
            f[4] = (_Float16)(v.x * sx); f[5] = (_Float16)(v.y * sx);
            f[6] = (_Float16)(v.z * sx); f[7] = (_Float16)(v.w * sx);
            ah[mf][ch] = f;
        }
    }

    float b1[2][4], b2[2][4];
    int   ic[2][4];
    #pragma unroll
    for (int mf = 0; mf < 2; ++mf)
        #pragma unroll
        for (int r = 0; r < 4; ++r) { b1[mf][r] = -2.0f; b2[mf][r] = -2.0f; ic[mf][r] = 0; }

    const char* ebase = enh + ((size_t)(q * 64 + h * 32)) * 16384;

    #pragma unroll
    for (int i = 0; i < 4; ++i) {
        int off = i * 4096 + wv * 1024 + ln * 16;
        async_load16(ebase + off, es[0] + off);
    }
    __syncthreads();

    for (int T = 0; T < 32; ++T) {
        if (T + 1 < 32) {
            const char* src = ebase + (size_t)(T + 1) * 16384;
            #pragma unroll
            for (int i = 0; i < 4; ++i) {
                int off = i * 4096 + wv * 1024 + ln * 16;
                async_load16(src + off, es[(T + 1) & 1] + off);
            }
        }
        const char* esb = es[T & 1];

        #pragma unroll
        for (int s = 0; s < 2; ++s) {
            const int  c  = s * 16 + l15;
            const char* cb = esb + c * 512;
            f16x8 bfr[8];
            #pragma unroll
            for (int ch = 0; ch < 8; ++ch)
                bfr[ch] = *(const f16x8*)(cb + ((((ch << 2) | qd) ^ c) << 4));

            f32x4 a0 = {0.f, 0.f, 0.f, 0.f};
            f32x4 a1 = {0.f, 0.f, 0.f, 0.f};
            #pragma unroll
            for (int ch = 0; ch < 8; ++ch) {
                a0 = __builtin_amdgcn_mfma_f32_16x16x32_f16(ah[0][ch], bfr[ch], a0, 0, 0, 0);
                a1 = __builtin_amdgcn_mfma_f32_16x16x32_f16(ah[1][ch], bfr[ch], a1, 0, 0, 0);
            }
            // code index within this q's codebook (global, incl. half offset)
            const int cg = (h << 10) | (T << 5) | (s << 4) | l15;
            #pragma unroll
            for (int r = 0; r < 4; ++r) {
                // exact top-2 update in 4 VALU ops: cmp, med3, max, cndmask.
                // invariant b1>=b2; med3(s,b1,b2) is precisely the new 2nd-best;
                // strict > keeps the earliest (smallest) index on fp ties.
                float s0 = a0[r];
                bool  g0 = s0 > b1[0][r];
                b2[0][r] = __builtin_amdgcn_fmed3f(s0, b1[0][r], b2[0][r]);
                b1[0][r] = fmaxf(b1[0][r], s0);
                ic[0][r] = g0 ? cg : ic[0][r];
                float s1 = a1[r];
                bool  g1 = s1 > b1[1][r];
                b2[1][r] = __builtin_amdgcn_fmed3f(s1, b1[1][r], b2[1][r]);
                b1[1][r] = fmaxf(b1[1][r], s1);
                ic[1][r] = g1 ? cg : ic[1][r];
            }
        }
        __syncthreads();
    }

    float fb1[2][4], fb2[2][4];
    int   fic[2][4];
    #pragma unroll
    for (int mf = 0; mf < 2; ++mf)
        #pragma unroll
        for (int r = 0; r < 4; ++r) {
            float v1 = b1[mf][r], v2 = b2[mf][r]; int vi = ic[mf][r];
            #pragma unroll
            for (int m = 1; m < 16; m <<= 1) {
                float o1 = __shfl_xor(v1, m, 64);
                float o2 = __shfl_xor(v2, m, 64);
                int   oi = __shfl_xor(vi, m, 64);
                if (o1 > v1 || (o1 == v1 && oi < vi)) { v2 = fmaxf(v1, o2); v1 = o1; vi = oi; }
                else v2 = fmaxf(v2, o1);
            }
            fb1[mf][r] = v1; fb2[mf][r] = v2; fic[mf][r] = vi;
        }

    if (l15 == 0) {
        #pragma unroll
        for (int mf = 0; mf < 2; ++mf)
            #pragma unroll
            for (int r = 0; r < 4; ++r) {
                int t = t0w + mf * 16 + qd * 4 + r;
                float4 pv;
                pv.x = fb1[mf][r];
                pv.y = fb2[mf][r];
                pv.z = __int_as_float(fic[mf][r]);
                pv.w = 0.f;
                part[(size_t)h * TT + t] = pv;
            }
    }
}

// ---------------- stage 1b: merge halves, encoding + list + gather-write ----
__global__ __launch_bounds__(256) void merge_kernel(const float* __restrict__ embed,
                                                    const float4* __restrict__ part,
                                                    float* __restrict__ out,
                                                    int* __restrict__ cnt,
                                                    int* __restrict__ list) {
    const int wv = threadIdx.x >> 6, ln = threadIdx.x & 63;
    const int nw = gridDim.x * 4;

    for (int t = blockIdx.x * 4 + wv; t < TT; t += nw) {
        float4 pa = part[t];          // half 0 (codes    0..1023)
        float4 pb = part[TT + t];     // half 1 (codes 1024..2047)
        // exact sorted-merge of two top-2 lists; tie -> half 0 (smaller index)
        float v1, v2; int vi;
        if (pb.x > pa.x) { v1 = pb.x; vi = __float_as_int(pb.z); v2 = fmaxf(pa.x, pb.y); }
        else             { v1 = pa.x; vi = __float_as_int(pa.z); v2 = fmaxf(pb.x, pa.y); }
        const int q = (t >> 11) & 3;

        if (ln == 0) {
            out[QUANT_ELEMS + (size_t)t] = (float)vi;
            if (v1 - v2 < THRESH) {
                int pos = atomicAdd(&cnt[q], 1);
                if (pos < CAP1Q) list[q * CAP1Q + pos] = t;
            }
        }
        const float* er = embed + ((size_t)(q * Kq + vi)) * Dq;
        float4 v = *(const float4*)(er + ln * 4);
        *(float4*)(out + (size_t)t * Dq + ln * 4) = v;
    }
    if (blockIdx.x == 0 && threadIdx.x == 0) out[QUANT_ELEMS + TT] = 0.0f;
}

// ---------------- stage 2a: exact partial argmax, 16 tokens x 256 codes -----
__global__ __launch_bounds__(256) void fix_partial(const float* __restrict__ x,
                                                   const float* __restrict__ enp,
                                                   const int* __restrict__ cnt,
                                                   const int* __restrict__ list,
                                                   float* __restrict__ pscore,
                                                   int* __restrict__ pcode) {
#pragma clang fp contract(off)
    __shared__ float xn[16][Dq];
    __shared__ int   stok[16];
    __shared__ float wp_s[4][16];
    __shared__ int   wp_c[4][16];

    const int tid = threadIdx.x;
    const int wv  = tid >> 6;
    const int ln  = tid & 63;

    int cq[4], nbq[4], total = 0;
    #pragma unroll
    for (int q = 0; q < 4; ++q) {
        int c = cnt[q]; if (c > CAP1Q) c = CAP1Q;
        cq[q] = c; nbq[q] = (c + 15) >> 4; total += nbq[q] * 8;
    }

    for (int j = blockIdx.x; j < total; j += gridDim.x) {
        int rem = j, q = 0;
        while (rem >= nbq[q] * 8) { rem -= nbq[q] * 8; ++q; }
        const int batch = rem >> 3, chunk = rem & 7;

        if (tid < 16) {
            int idx = batch * 16 + tid;
            stok[tid] = list[q * CAP1Q + (idx < cq[q] ? idx : batch * 16)];
        }
        __syncthreads();
        // stage numpy-normalized x rows (wave handles 4 rows)
        for (int r = 0; r < 4; ++r) {
            int i = wv * 4 + r;
            const float* xr = x + (size_t)stok[i] * Dq;
            float nm = np_norm_wave(xr, ln);
            #pragma unroll
            for (int e = 0; e < 4; ++e)
                xn[i][ln * 4 + e] = f32_div(xr[ln * 4 + e], nm);
        }
        __syncthreads();

        const int c = chunk * 256 + tid;
        const float* er = enp + ((size_t)(q * Kq + c)) * Dq;
        float l0[16], l1[16], l2[16], l3[16];
        #pragma unroll
        for (int i = 0; i < 16; ++i) { l0[i] = 0.f; l1[i] = 0.f; l2[i] = 0.f; l3[i] = 0.f; }

        for (int d = 0; d < Dq; d += 4) {
            float4 e = *(const float4*)(er + d);
            #pragma unroll
            for (int i = 0; i < 16; ++i) {
                float4 xv = *(const float4*)&xn[i][d];   // wave-broadcast LDS read
                l0[i] = l0[i] + xv.x * e.x;
                l1[i] = l1[i] + xv.y * e.y;
                l2[i] = l2[i] + xv.z * e.z;
                l3[i] = l3[i] + xv.w * e.w;
            }
        }

        #pragma unroll
        for (int i = 0; i < 16; ++i) {
            float s = (l0[i] + l1[i]) + (l2[i] + l3[i]);   // numpy SSE tree
            int bc = c;
            #pragma unroll
            for (int m = 1; m < 64; m <<= 1) {
                float os = __shfl_xor(s, m, 64);
                int   oc = __shfl_xor(bc, m, 64);
                if (os > s || (os == s && oc < bc)) { s = os; bc = oc; }
            }
            if (ln == 0) { wp_s[wv][i] = s; wp_c[wv][i] = bc; }
        }
        __syncthreads();
        if (tid < 16) {
            int idx = batch * 16 + tid;
            if (idx < cq[q]) {
                float s = wp_s[0][tid]; int bc = wp_c[0][tid];
                #pragma unroll
                for (int w2 = 1; w2 < 4; ++w2) {
                    float os = wp_s[w2][tid]; int oc = wp_c[w2][tid];
                    if (os > s || (os == s && oc < bc)) { s = os; bc = oc; }
                }
                int p = q * CAP1Q + idx;
                pscore[p * 8 + chunk] = s;
                pcode[p * 8 + chunk]  = bc;
            }
        }
        __syncthreads();
    }
}

// ---------------- stage 2b: merge partials, write encoding + row ------------
__global__ __launch_bounds__(256) void fix_final(const float* __restrict__ embed,
                                                 const int* __restrict__ cnt,
                                                 const int* __restrict__ list,
                                                 const float* __restrict__ pscore,
                                                 const int* __restrict__ pcode,
                                                 float* __restrict__ out) {
    int cq[4], tot = 0;
    #pragma unroll
    for (int q = 0; q < 4; ++q) {
        int c = cnt[q]; if (c > CAP1Q) c = CAP1Q;
        cq[q] = c; tot += c;
    }
    const int wv = threadIdx.x >> 6, ln = threadIdx.x & 63;

    for (int j = blockIdx.x * 4 + wv; j < tot; j += gridDim.x * 4) {
        int rem = j, q = 0;
        while (rem >= cq[q]) { rem -= cq[q]; ++q; }
        int p = q * CAP1Q + rem;
        int t = list[p];
        int bc = 0;
        if (ln == 0) {
            float bs = pscore[p * 8]; bc = pcode[p * 8];
            #pragma unroll
            for (int ch = 1; ch < 8; ++ch) {
                float s = pscore[p * 8 + ch]; int c2 = pcode[p * 8 + ch];
                if (s > bs || (s == bs && c2 < bc)) { bs = s; bc = c2; }
            }
            out[QUANT_ELEMS + (size_t)t] = (float)bc;
        }
        bc = __shfl(bc, 0, 64);
        const float* er = embed + ((size_t)(q * Kq + bc)) * Dq;
        float4 v = *(const float4*)(er + ln * 4);
        *(float4*)(out + (size_t)t * Dq + ln * 4) = v;
    }
}

extern "C" void kernel_launch(void* const* d_in, const int* in_sizes, int n_in,
                              void* d_out, int out_size, void* d_ws, size_t ws_size,
                              hipStream_t stream) {
    const float* x     = (const float*)d_in[0];
    const float* embed = (const float*)d_in[1];
    float* out = (float*)d_out;
    char*  ws  = (char*)d_ws;
    int*    cnt    = (int*)(ws + WS_CNT_OFF);
    int*    list   = (int*)(ws + WS_LIST_OFF);
    float*  pscore = (float*)(ws + WS_PSC_OFF);
    int*    pcode  = (int*)(ws + WS_PCD_OFF);
    char*   enh    = ws + WS_ENH_OFF;
    float*  enp    = (float*)(ws + WS_ENP_OFF);
    float4* part   = (float4*)(ws + WS_PART_OFF);

    hipMemsetAsync(cnt, 0, 16, stream);
    prep_kernel<<<(Qq * Kq) / 4, 256, 0, stream>>>(embed, enh, enp);
    gemm_kernel<<<1024, 256, 0, stream>>>(x, enh, part);
    merge_kernel<<<2048, 256, 0, stream>>>(embed, part, out, cnt, list);
    fix_partial<<<1024, 256, 0, stream>>>(x, enp, cnt, list, pscore, pcode);
    fix_final<<<256, 256, 0, stream>>>(embed, cnt, list, pscore, pcode, out);
}